// Round 6
// baseline (331.690 us; speedup 1.0000x reference)
//
#include <hip/hip_runtime.h>
#include <hip/hip_bf16.h>
#include <math.h>

// B=2, LQ=LM=2048, D=1024, H=16, DH=64. f32 I/O, bf16 MFMA internal.
// cvt(activations) + transpose(weights) -> QKV GEMMs (global_load_lds) ->
// flash attn (16 rows/wave, 4 waves/SIMD) -> out GEMM.

typedef __bf16 bf16;
typedef __bf16 bf16x4 __attribute__((ext_vector_type(4)));
typedef __bf16 bf16x8 __attribute__((ext_vector_type(8)));
typedef float f32x4 __attribute__((ext_vector_type(4)));

#define MFMA16(a, b, c) __builtin_amdgcn_mfma_f32_16x16x32_bf16((a), (b), (c), 0, 0, 0)

__device__ inline float exp2_hw(float x) {
    float r; asm("v_exp_f32 %0, %1" : "=v"(r) : "v"(x)); return r;   // 2^x
}

__device__ inline void gload_lds16(const bf16* g, bf16* l) {
    __builtin_amdgcn_global_load_lds(
        (const __attribute__((address_space(1))) void*)g,
        (__attribute__((address_space(3))) void*)l, 16, 0, 0);
}

// ---------------------------------------------------------------------------
// Activations f32 -> bf16. 4.19M elems each; grid (2048, 2), 8 elems/thread.
// ---------------------------------------------------------------------------
__global__ __launch_bounds__(256) void cvt_kernel(
    const float* __restrict__ X0, const float* __restrict__ X1,
    bf16* __restrict__ Y0, bf16* __restrict__ Y1)
{
    const float* X = blockIdx.y ? X1 : X0;
    bf16* Y = blockIdx.y ? Y1 : Y0;
    const size_t i = ((size_t)blockIdx.x * 256 + threadIdx.x) * 8;
    float4 f0 = *(const float4*)&X[i];
    float4 f1 = *(const float4*)&X[i + 4];
    bf16x8 h;
    h[0] = (bf16)f0.x; h[1] = (bf16)f0.y; h[2] = (bf16)f0.z; h[3] = (bf16)f0.w;
    h[4] = (bf16)f1.x; h[5] = (bf16)f1.y; h[6] = (bf16)f1.z; h[7] = (bf16)f1.w;
    *(bf16x8*)&Y[i] = h;
}

// ---------------------------------------------------------------------------
// Weight transpose + f32->bf16: WT[n][k] = (bf16)W[k][n], 1024x1024 each.
// ---------------------------------------------------------------------------
__global__ __launch_bounds__(256) void transpose_cvt_kernel(
    const float* __restrict__ W0, const float* __restrict__ W1,
    const float* __restrict__ W2, const float* __restrict__ W3,
    bf16* __restrict__ T0, bf16* __restrict__ T1,
    bf16* __restrict__ T2, bf16* __restrict__ T3)
{
    __shared__ float Ls[64][65];
    const float* W; bf16* T;
    switch (blockIdx.z) {
        case 0:  W = W0; T = T0; break;
        case 1:  W = W1; T = T1; break;
        case 2:  W = W2; T = T2; break;
        default: W = W3; T = T3; break;
    }
    const int t = threadIdx.x;
    const int n0 = blockIdx.x * 64, k0 = blockIdx.y * 64;
    const int g = t >> 4, c = (t & 15) * 4;

    #pragma unroll
    for (int p = 0; p < 4; ++p) {
        const int row = p * 16 + g;
        float4 f = *(const float4*)&W[(size_t)(k0 + row) * 1024 + n0 + c];
        Ls[row][c + 0] = f.x; Ls[row][c + 1] = f.y;
        Ls[row][c + 2] = f.z; Ls[row][c + 3] = f.w;
    }
    __syncthreads();
    #pragma unroll
    for (int p = 0; p < 4; ++p) {
        const int n = p * 16 + g;
        bf16x4 h;
        h[0] = (bf16)Ls[c + 0][n]; h[1] = (bf16)Ls[c + 1][n];
        h[2] = (bf16)Ls[c + 2][n]; h[3] = (bf16)Ls[c + 3][n];
        *(bf16x4*)&T[(size_t)(n0 + n) * 1024 + k0 + c] = h;
    }
}

// ---------------------------------------------------------------------------
// GEMM: out = (A[M,1024](bf16) @ W + bias) * alpha, W as WT[n][k] bf16.
// BM=128, BN=64, BK=64; grid (16,32)=512 blocks (2/CU). 4 waves, 64x32 each.
// Staging via global_load_lds(16B): linear LDS dest, XOR-swizzled global src;
// ds_read_b128 fragments apply the same XOR -> ~2-way (free) bank access.
// mode 0: out[m][n]; mode 1: per-batch transposed out[b][n][t], m=b*2048+t.
// ---------------------------------------------------------------------------
template <typename TO>
__global__ __launch_bounds__(256) void gemm_kernel(
    const bf16* __restrict__ A, const bf16* __restrict__ WT,
    const float* __restrict__ bias, TO* __restrict__ out,
    float alpha, int mode)
{
    __shared__ __align__(16) bf16 As[128 * 64];
    __shared__ __align__(16) bf16 Bs[64 * 64];

    const int fid = blockIdx.x + (blockIdx.y << 4);
    const int swz = (fid & 7) * 64 + (fid >> 3);     // bijective, 512 % 8 == 0
    const int n0 = (swz & 15) * 64;
    const int m0 = (swz >> 4) * 128;

    const int tid = threadIdx.x;
    const int w = tid >> 6, lane = tid & 63;
    const int lr = lane & 15, lg = lane >> 4;
    const int wm = (w >> 1) * 64, wn = (w & 1) * 32;

    const int arow0 = w * 32 + (lane >> 3);          // A-stage row base (+8/p)
    const int brow0 = w * 16 + (lane >> 3);          // B-stage row base (+8/p)
    const int sch = lane & 7;                        // LDS chunk (linear dest)

    f32x4 acc[4][2] = {};

    #pragma unroll 1
    for (int kt = 0; kt < 1024; kt += 64) {
        #pragma unroll
        for (int p = 0; p < 4; ++p) {
            const int row = arow0 + p * 8;
            const int xc = ((sch ^ (row & 7)) << 3);     // swizzled src chunk
            gload_lds16(&A[(size_t)(m0 + row) * 1024 + kt + xc],
                        &As[row * 64 + sch * 8]);
        }
        #pragma unroll
        for (int p = 0; p < 2; ++p) {
            const int row = brow0 + p * 8;
            const int xc = ((sch ^ (row & 7)) << 3);
            gload_lds16(&WT[(size_t)(n0 + row) * 1024 + kt + xc],
                        &Bs[row * 64 + sch * 8]);
        }
        __syncthreads();

        #pragma unroll
        for (int ks = 0; ks < 2; ++ks) {
            const int c = (((ks * 4 + lg) ^ (lr & 7)) << 3);   // un-swizzle
            bf16x8 af[4], bfv[2];
            #pragma unroll
            for (int mt = 0; mt < 4; ++mt)
                af[mt] = *(const bf16x8*)&As[(wm + mt * 16 + lr) * 64 + c];
            #pragma unroll
            for (int nt = 0; nt < 2; ++nt)
                bfv[nt] = *(const bf16x8*)&Bs[(wn + nt * 16 + lr) * 64 + c];
            #pragma unroll
            for (int nt = 0; nt < 2; ++nt)
                #pragma unroll
                for (int mt = 0; mt < 4; ++mt)
                    acc[mt][nt] = MFMA16(af[mt], bfv[nt], acc[mt][nt]);
        }
        __syncthreads();
    }

    #pragma unroll
    for (int nt = 0; nt < 2; ++nt) {
        const int n = n0 + wn + nt * 16 + lr;
        const float bv = bias[n];
        #pragma unroll
        for (int mt = 0; mt < 4; ++mt) {
            #pragma unroll
            for (int i = 0; i < 4; ++i) {
                const int m = m0 + wm + mt * 16 + lg * 4 + i;
                const float v = (acc[mt][nt][i] + bv) * alpha;
                if (mode == 0) {
                    out[(size_t)m * 1024 + n] = (TO)v;
                } else {
                    const int b = m >> 11, t = m & 2047;
                    out[((size_t)(b << 10) + n) * 2048 + t] = (TO)v;
                }
            }
        }
    }
}

// ---------------------------------------------------------------------------
// Flash attention v3. Grid (32,16,2) = 1024 blocks -> 4 blocks/CU,
// 4 waves x 16 q-rows -> 4 waves/SIMD. Defer-max softmax (no cross-lane
// reduce in common path), l via ones-column MFMA, log2-domain exp,
// K/bias prefetch, wave-private P in LDS.
// ---------------------------------------------------------------------------
__global__ __launch_bounds__(256, 4) void attn_kernel(
    const bf16* __restrict__ Q, const bf16* __restrict__ K,
    const bf16* __restrict__ Vt, const float* __restrict__ mbias,
    bf16* __restrict__ Oout)
{
    __shared__ __align__(16) bf16 Ps[4][16][72];   // wave-private, 144B rows

    const int tid = threadIdx.x;
    const int w = tid >> 6, lane = tid & 63;
    const int lr = lane & 15, lg = lane >> 4;

    // XCD swizzle: each XCD gets 4 (h,b) groups x all 32 q-tiles -> 2MB K+V in L2
    const int fid = blockIdx.x + (blockIdx.y << 5) + (blockIdx.z << 9);
    const int swz = (fid & 7) * 128 + (fid >> 3);
    const int qt = swz & 31, h = (swz >> 5) & 15, b = swz >> 9;
    const int qrow = qt * 64 + w * 16;

    const size_t qoff = (size_t)(b * 2048 + qrow + lr) * 1024 + h * 64;
    bf16x8 qf[2];
    qf[0] = *(const bf16x8*)&Q[qoff + lg * 8];
    qf[1] = *(const bf16x8*)&Q[qoff + 32 + lg * 8];

    const bf16* kp = K + (size_t)b * 2048 * 1024 + h * 64 + (size_t)lr * 1024 + lg * 8;
    const bf16* vp = Vt + ((size_t)b * 1024 + h * 64 + lr) * 2048 + lg * 8;
    const float* bp = mbias + b * 2048 + lr;

    float m_run[4];
    f32x4 of[4] = {};
    f32x4 ofl = {};
    #pragma unroll
    for (int i = 0; i < 4; ++i) m_run[i] = -INFINITY;

    bf16x8 ones8;
    #pragma unroll
    for (int j = 0; j < 8; ++j) ones8[j] = (bf16)1.0f;

    // preload K tile 0 + bias tile 0 (bias pre-scaled to log2 domain)
    bf16x8 kf[2][4];
    #pragma unroll
    for (int ks = 0; ks < 2; ++ks)
        #pragma unroll
        for (int nt = 0; nt < 4; ++nt)
            kf[ks][nt] = *(const bf16x8*)&kp[(size_t)nt * 16384 + ks * 32];
    float bvv[4];
    #pragma unroll
    for (int nt = 0; nt < 4; ++nt) bvv[nt] = bp[nt * 16] * 1.44269504f;

    #pragma unroll 1
    for (int it = 0; it < 32; ++it) {
        // ---- V(t) loads first (consumed at the bottom) ----
        bf16x8 vf[2][4];
        #pragma unroll
        for (int ks = 0; ks < 2; ++ks)
            #pragma unroll
            for (int dt = 0; dt < 4; ++dt)
                vf[ks][dt] = *(const bf16x8*)&vp[(size_t)dt * 32768 + ks * 32];

        // ---- S = Q K^T ----
        f32x4 s[4] = {};
        __builtin_amdgcn_s_setprio(1);
        #pragma unroll
        for (int ks = 0; ks < 2; ++ks)
            #pragma unroll
            for (int nt = 0; nt < 4; ++nt)
                s[nt] = MFMA16(qf[ks], kf[ks][nt], s[nt]);
        __builtin_amdgcn_s_setprio(0);

        // ---- prefetch K(t+1) (last-iter overrun stays inside workspace) ----
        kp += 65536;
        #pragma unroll
        for (int ks = 0; ks < 2; ++ks)
            #pragma unroll
            for (int nt = 0; nt < 4; ++nt)
                kf[ks][nt] = *(const bf16x8*)&kp[(size_t)nt * 16384 + ks * 32];

        // ---- bias add + in-lane row max; defer-max check ----
        float rml[4];
        #pragma unroll
        for (int i = 0; i < 4; ++i) {
            float a0 = s[0][i] + bvv[0], a1 = s[1][i] + bvv[1];
            float a2 = s[2][i] + bvv[2], a3 = s[3][i] + bvv[3];
            s[0][i] = a0; s[1][i] = a1; s[2][i] = a2; s[3][i] = a3;
            rml[i] = fmaxf(fmaxf(a0, a1), fmaxf(a2, a3));
        }
        bool need = false;
        #pragma unroll
        for (int i = 0; i < 4; ++i)
            need = need || (rml[i] > m_run[i] + 8.f);

        if (__any(need)) {        // rare: full reduce + rescale
            #pragma unroll
            for (int off = 1; off < 16; off <<= 1)
                #pragma unroll
                for (int i = 0; i < 4; ++i)
                    rml[i] = fmaxf(rml[i], __shfl_xor(rml[i], off, 64));
            #pragma unroll
            for (int i = 0; i < 4; ++i) {
                const float mnew = fmaxf(m_run[i], rml[i]);
                const float al = exp2_hw(m_run[i] - mnew);
                m_run[i] = mnew;
                ofl[i] *= al;
                #pragma unroll
                for (int dt = 0; dt < 4; ++dt) of[dt][i] *= al;
            }
        }

        // ---- prefetch bias(t+1) (guarded: input buffer ends exactly) ----
        bp += (it < 31) ? 64 : 0;
        #pragma unroll
        for (int nt = 0; nt < 4; ++nt) bvv[nt] = bp[nt * 16] * 1.44269504f;

        // ---- P = exp2(S - m) -> wave-private LDS ----
        #pragma unroll
        for (int nt = 0; nt < 4; ++nt)
            #pragma unroll
            for (int i = 0; i < 4; ++i) {
                const float p = exp2_hw(s[nt][i] - m_run[i]);
                Ps[w][lg * 4 + i][nt * 16 + lr] = (bf16)p;
            }

        // ---- O += P V ; l += P * ones ----
        bf16x8 pa0 = *(const bf16x8*)&Ps[w][lr][lg * 8];
        bf16x8 pa1 = *(const bf16x8*)&Ps[w][lr][32 + lg * 8];
        __builtin_amdgcn_s_setprio(1);
        #pragma unroll
        for (int dt = 0; dt < 4; ++dt) of[dt] = MFMA16(pa0, vf[0][dt], of[dt]);
        ofl = MFMA16(pa0, ones8, ofl);
        #pragma unroll
        for (int dt = 0; dt < 4; ++dt) of[dt] = MFMA16(pa1, vf[1][dt], of[dt]);
        ofl = MFMA16(pa1, ones8, ofl);
        __builtin_amdgcn_s_setprio(0);

        vp += 64;
    }

    // ---- finalize: O / l ----
    const size_t ob = (size_t)(b * 2048 + qrow + lg * 4) * 1024 + h * 64;
    #pragma unroll
    for (int i = 0; i < 4; ++i) {
        const float inv = 1.0f / ofl[i];
        #pragma unroll
        for (int dt = 0; dt < 4; ++dt)
            Oout[ob + (size_t)i * 1024 + dt * 16 + lr] = (bf16)(of[dt][i] * inv);
    }
}

// ---------------------------------------------------------------------------
extern "C" void kernel_launch(void* const* d_in, const int* in_sizes, int n_in,
                              void* d_out, int out_size, void* d_ws, size_t ws_size,
                              hipStream_t stream) {
    const float* query  = (const float*)d_in[0];
    const float* memory = (const float*)d_in[1];
    const float* mbias  = (const float*)d_in[2];
    const float* Wq = (const float*)d_in[3];
    const float* bq = (const float*)d_in[4];
    const float* Wk = (const float*)d_in[5];
    const float* bk = (const float*)d_in[6];
    const float* Wv = (const float*)d_in[7];
    const float* bv = (const float*)d_in[8];
    const float* Wo = (const float*)d_in[9];
    const float* bo = (const float*)d_in[10];
    float* out = (float*)d_out;

    const size_t SZ = 4096ull * 1024ull * sizeof(bf16);   // 8 MiB
    const size_t WZ = 1024ull * 1024ull * sizeof(bf16);   // 2 MiB
    char* ws = (char*)d_ws;
    bf16* Qp  = (bf16*)(ws);
    bf16* Kp  = (bf16*)(ws + SZ);       // also reused as query_bf16 staging
    bf16* Vtp = (bf16*)(ws + 2 * SZ);
    bf16* Ap  = (bf16*)(ws + 3 * SZ);   // also reused as memory_bf16 staging
    bf16* WTq = (bf16*)(ws + 4 * SZ);
    bf16* WTk = (bf16*)(ws + 4 * SZ + WZ);
    bf16* WTv = (bf16*)(ws + 4 * SZ + 2 * WZ);
    bf16* WTo = (bf16*)(ws + 4 * SZ + 3 * WZ);

    dim3 blk(256);
    // activations f32->bf16: query -> Kp(buf), memory -> Ap(buf)
    cvt_kernel<<<dim3(2048, 2), blk, 0, stream>>>(query, memory, Kp, Ap);
    transpose_cvt_kernel<<<dim3(16, 16, 4), blk, 0, stream>>>(
        Wq, Wk, Wv, Wo, WTq, WTk, WTv, WTo);

    dim3 gg(16, 32);
    // Q scaled by DH^-0.5 * log2(e): softmax runs in exp2 domain.
    gemm_kernel<bf16><<<gg, blk, 0, stream>>>(Kp, WTq, bq, Qp,  0.18033688f, 0);
    gemm_kernel<bf16><<<gg, blk, 0, stream>>>(Ap, WTk, bk, Kp,  1.0f, 0);  // frees Kp buf use
    gemm_kernel<bf16><<<gg, blk, 0, stream>>>(Ap, WTv, bv, Vtp, 1.0f, 1);
    attn_kernel<<<dim3(32, 16, 2), blk, 0, stream>>>(Qp, Kp, Vtp, mbias, Ap);
    gemm_kernel<float><<<gg, blk, 0, stream>>>(Ap, WTo, bo, out, 1.0f, 0);
}

// Round 7
// 159.810 us; speedup vs baseline: 2.0755x; 2.0755x over previous
//
#include <hip/hip_runtime.h>
#include <hip/hip_bf16.h>
#include <math.h>

// B=2, LQ=LM=2048, D=1024, H=16, DH=64. f32 I/O, bf16 MFMA internal.
// cvt(acts) + transpose(weights) -> QKV GEMMs (global_load_lds) ->
// flash attn (block-shared LDS K/V staging, counted-vmcnt pipeline) -> out GEMM.

typedef __bf16 bf16;
typedef __bf16 bf16x4 __attribute__((ext_vector_type(4)));
typedef __bf16 bf16x8 __attribute__((ext_vector_type(8)));
typedef float f32x4 __attribute__((ext_vector_type(4)));

#define MFMA16(a, b, c) __builtin_amdgcn_mfma_f32_16x16x32_bf16((a), (b), (c), 0, 0, 0)

__device__ inline float exp2_hw(float x) {
    float r; asm("v_exp_f32 %0, %1" : "=v"(r) : "v"(x)); return r;   // 2^x
}

__device__ inline void gload_lds16(const bf16* g, bf16* l) {
    __builtin_amdgcn_global_load_lds(
        (const __attribute__((address_space(1))) void*)g,
        (__attribute__((address_space(3))) void*)l, 16, 0, 0);
}

// ---------------------------------------------------------------------------
// Activations f32 -> bf16. 4.19M elems each; grid (2048, 2), 8 elems/thread.
// ---------------------------------------------------------------------------
__global__ __launch_bounds__(256) void cvt_kernel(
    const float* __restrict__ X0, const float* __restrict__ X1,
    bf16* __restrict__ Y0, bf16* __restrict__ Y1)
{
    const float* X = blockIdx.y ? X1 : X0;
    bf16* Y = blockIdx.y ? Y1 : Y0;
    const size_t i = ((size_t)blockIdx.x * 256 + threadIdx.x) * 8;
    float4 f0 = *(const float4*)&X[i];
    float4 f1 = *(const float4*)&X[i + 4];
    bf16x8 h;
    h[0] = (bf16)f0.x; h[1] = (bf16)f0.y; h[2] = (bf16)f0.z; h[3] = (bf16)f0.w;
    h[4] = (bf16)f1.x; h[5] = (bf16)f1.y; h[6] = (bf16)f1.z; h[7] = (bf16)f1.w;
    *(bf16x8*)&Y[i] = h;
}

// ---------------------------------------------------------------------------
// Weight transpose + f32->bf16: WT[n][k] = (bf16)W[k][n], 1024x1024 each.
// ---------------------------------------------------------------------------
__global__ __launch_bounds__(256) void transpose_cvt_kernel(
    const float* __restrict__ W0, const float* __restrict__ W1,
    const float* __restrict__ W2, const float* __restrict__ W3,
    bf16* __restrict__ T0, bf16* __restrict__ T1,
    bf16* __restrict__ T2, bf16* __restrict__ T3)
{
    __shared__ float Ls[64][65];
    const float* W; bf16* T;
    switch (blockIdx.z) {
        case 0:  W = W0; T = T0; break;
        case 1:  W = W1; T = T1; break;
        case 2:  W = W2; T = T2; break;
        default: W = W3; T = T3; break;
    }
    const int t = threadIdx.x;
    const int n0 = blockIdx.x * 64, k0 = blockIdx.y * 64;
    const int g = t >> 4, c = (t & 15) * 4;

    #pragma unroll
    for (int p = 0; p < 4; ++p) {
        const int row = p * 16 + g;
        float4 f = *(const float4*)&W[(size_t)(k0 + row) * 1024 + n0 + c];
        Ls[row][c + 0] = f.x; Ls[row][c + 1] = f.y;
        Ls[row][c + 2] = f.z; Ls[row][c + 3] = f.w;
    }
    __syncthreads();
    #pragma unroll
    for (int p = 0; p < 4; ++p) {
        const int n = p * 16 + g;
        bf16x4 h;
        h[0] = (bf16)Ls[c + 0][n]; h[1] = (bf16)Ls[c + 1][n];
        h[2] = (bf16)Ls[c + 2][n]; h[3] = (bf16)Ls[c + 3][n];
        *(bf16x4*)&T[(size_t)(n0 + n) * 1024 + k0 + c] = h;
    }
}

// ---------------------------------------------------------------------------
// GEMM: out = (A[M,1024](bf16) @ W + bias) * alpha, W as WT[n][k] bf16.
// BM=128, BN=64, BK=64; grid (16,32)=512 blocks. global_load_lds staging,
// source-side XOR swizzle, swizzled ds_read_b128 fragments.
// ---------------------------------------------------------------------------
template <typename TO>
__global__ __launch_bounds__(256) void gemm_kernel(
    const bf16* __restrict__ A, const bf16* __restrict__ WT,
    const float* __restrict__ bias, TO* __restrict__ out,
    float alpha, int mode)
{
    __shared__ __align__(16) bf16 As[128 * 64];
    __shared__ __align__(16) bf16 Bs[64 * 64];

    const int fid = blockIdx.x + (blockIdx.y << 4);
    const int swz = (fid & 7) * 64 + (fid >> 3);
    const int n0 = (swz & 15) * 64;
    const int m0 = (swz >> 4) * 128;

    const int tid = threadIdx.x;
    const int w = tid >> 6, lane = tid & 63;
    const int lr = lane & 15, lg = lane >> 4;
    const int wm = (w >> 1) * 64, wn = (w & 1) * 32;

    const int arow0 = w * 32 + (lane >> 3);
    const int brow0 = w * 16 + (lane >> 3);
    const int sch = lane & 7;

    f32x4 acc[4][2] = {};

    #pragma unroll 1
    for (int kt = 0; kt < 1024; kt += 64) {
        #pragma unroll
        for (int p = 0; p < 4; ++p) {
            const int row = arow0 + p * 8;
            const int xc = ((sch ^ (row & 7)) << 3);
            gload_lds16(&A[(size_t)(m0 + row) * 1024 + kt + xc],
                        &As[row * 64 + sch * 8]);
        }
        #pragma unroll
        for (int p = 0; p < 2; ++p) {
            const int row = brow0 + p * 8;
            const int xc = ((sch ^ (row & 7)) << 3);
            gload_lds16(&WT[(size_t)(n0 + row) * 1024 + kt + xc],
                        &Bs[row * 64 + sch * 8]);
        }
        __syncthreads();

        #pragma unroll
        for (int ks = 0; ks < 2; ++ks) {
            const int c = (((ks * 4 + lg) ^ (lr & 7)) << 3);
            bf16x8 af[4], bfv[2];
            #pragma unroll
            for (int mt = 0; mt < 4; ++mt)
                af[mt] = *(const bf16x8*)&As[(wm + mt * 16 + lr) * 64 + c];
            #pragma unroll
            for (int nt = 0; nt < 2; ++nt)
                bfv[nt] = *(const bf16x8*)&Bs[(wn + nt * 16 + lr) * 64 + c];
            #pragma unroll
            for (int nt = 0; nt < 2; ++nt)
                #pragma unroll
                for (int mt = 0; mt < 4; ++mt)
                    acc[mt][nt] = MFMA16(af[mt], bfv[nt], acc[mt][nt]);
        }
        __syncthreads();
    }

    #pragma unroll
    for (int nt = 0; nt < 2; ++nt) {
        const int n = n0 + wn + nt * 16 + lr;
        const float bv = bias[n];
        #pragma unroll
        for (int mt = 0; mt < 4; ++mt) {
            #pragma unroll
            for (int i = 0; i < 4; ++i) {
                const int m = m0 + wm + mt * 16 + lg * 4 + i;
                const float v = (acc[mt][nt][i] + bv) * alpha;
                if (mode == 0) {
                    out[(size_t)m * 1024 + n] = (TO)v;
                } else {
                    const int b = m >> 11, t = m & 2047;
                    out[((size_t)(b << 10) + n) * 2048 + t] = (TO)v;
                }
            }
        }
    }
}

// ---------------------------------------------------------------------------
// Flash attention v4. Grid (16,16,2)=512 blocks, 4 waves x 32 q-rows.
// K/V tiles staged ONCE per block into double-buffered LDS via async
// global_load_lds (prefetch tile t+1 during compute of t, counted vmcnt(4),
// raw s_barrier). XOR-swizzled tiles -> bank-optimal ds_read_b128 fragments.
// Defer-max softmax (no cross-lane reduce in common path), l via ones-MFMA,
// log2-domain exp, wave-private P (stride-76: conflict-free).
// ---------------------------------------------------------------------------
__global__ __launch_bounds__(256) void attn_kernel(
    const bf16* __restrict__ Q, const bf16* __restrict__ K,
    const bf16* __restrict__ Vt, const float* __restrict__ mbias,
    bf16* __restrict__ Oout)
{
    __shared__ __align__(16) bf16 Kbuf[2][4096];   // 64 keys x 64 d, swizzled
    __shared__ __align__(16) bf16 Vbuf[2][4096];   // 64 d x 64 keys, swizzled
    __shared__ bf16 Ps[4][32][76];                 // wave-private P

    const int tid = threadIdx.x;
    const int w = tid >> 6, lane = tid & 63;
    const int lr = lane & 15, lg = lane >> 4;

    // XCD swizzle: each XCD -> 4 (h,b) groups (2MB K+V, L2-resident)
    const int fid = blockIdx.x + (blockIdx.y << 4) + (blockIdx.z << 8);
    const int swz = (fid & 7) * 64 + (fid >> 3);
    const int qt = swz & 15, h = (swz >> 4) & 15, b = swz >> 8;
    const int qrow = qt * 128 + w * 32;

    // Q fragments (2 m-frags x 2 k-slices)
    bf16x8 qf[2][2];
    #pragma unroll
    for (int mf = 0; mf < 2; ++mf) {
        const size_t qo = (size_t)(b * 2048 + qrow + mf * 16 + lr) * 1024 + h * 64;
        qf[mf][0] = *(const bf16x8*)&Q[qo + lg * 8];
        qf[mf][1] = *(const bf16x8*)&Q[qo + 32 + lg * 8];
    }

    const bf16* Kb = K + (size_t)b * 2048 * 1024 + h * 64;
    const bf16* Vb = Vt + ((size_t)b * 1024 + h * 64) * 2048;
    const float* bp = mbias + b * 2048 + lr;

    float m_run[2][4];
    f32x4 of[2][4] = {};
    f32x4 ofl[2] = {};
    #pragma unroll
    for (int mf = 0; mf < 2; ++mf)
        #pragma unroll
        for (int i = 0; i < 4; ++i) m_run[mf][i] = -INFINITY;

    bf16x8 ones8;
    #pragma unroll
    for (int j = 0; j < 8; ++j) ones8[j] = (bf16)1.0f;

    // stage tile t into buffer bi: 512 16B-chunks per tile, 4 waves x 2 rounds.
    // LDS dest linear (wave base + lane*16); SOURCE chunk XOR-swizzled (rule 21).
    auto stage = [&](int t, int bi) {
        #pragma unroll
        for (int r = 0; r < 2; ++r) {
            const int chunk = w * 128 + r * 64 + lane;
            const int R = chunk >> 3, cs = (chunk & 7) ^ (R & 7);
            gload_lds16(Kb + (size_t)(t * 64 + R) * 1024 + cs * 8,
                        &Kbuf[bi][chunk * 8]);
        }
        #pragma unroll
        for (int r = 0; r < 2; ++r) {
            const int chunk = w * 128 + r * 64 + lane;
            const int R = chunk >> 3, cs = (chunk & 7) ^ (R & 7);
            gload_lds16(Vb + (size_t)R * 2048 + t * 64 + cs * 8,
                        &Vbuf[bi][chunk * 8]);
        }
    };

    stage(0, 0);
    float bvv[4];
    #pragma unroll
    for (int nt = 0; nt < 4; ++nt) bvv[nt] = bp[nt * 16] * 1.44269504f;

    #pragma unroll 1
    for (int it = 0; it < 32; ++it) {
        const int cur = it & 1;
        stage(it < 31 ? it + 1 : 31, cur ^ 1);     // async prefetch next tile
        asm volatile("s_waitcnt vmcnt(4)" ::: "memory");  // cur's stage landed
        __builtin_amdgcn_s_barrier();
        __builtin_amdgcn_sched_barrier(0);

        // ---- K fragments from LDS (swizzled read) + QK^T ----
        f32x4 s[2][4] = {};
        #pragma unroll
        for (int ks = 0; ks < 2; ++ks) {
            const int cw = (((ks * 4 + lg) ^ (lr & 7)) << 3);
            bf16x8 kf[4];
            #pragma unroll
            for (int nt = 0; nt < 4; ++nt)
                kf[nt] = *(const bf16x8*)&Kbuf[cur][(nt * 16 + lr) * 64 + cw];
            __builtin_amdgcn_s_setprio(1);
            #pragma unroll
            for (int nt = 0; nt < 4; ++nt) {
                s[0][nt] = MFMA16(qf[0][ks], kf[nt], s[0][nt]);
                s[1][nt] = MFMA16(qf[1][ks], kf[nt], s[1][nt]);
            }
            __builtin_amdgcn_s_setprio(0);
        }

        // ---- V fragments from LDS (consumed in PV below) ----
        bf16x8 vf[2][4];
        #pragma unroll
        for (int ks = 0; ks < 2; ++ks) {
            const int cw = (((ks * 4 + lg) ^ (lr & 7)) << 3);
            #pragma unroll
            for (int dt = 0; dt < 4; ++dt)
                vf[ks][dt] = *(const bf16x8*)&Vbuf[cur][(dt * 16 + lr) * 64 + cw];
        }

        // ---- bias add + in-lane row max; defer-max check ----
        float rml[2][4];
        #pragma unroll
        for (int mf = 0; mf < 2; ++mf)
            #pragma unroll
            for (int i = 0; i < 4; ++i) {
                float a0 = s[mf][0][i] + bvv[0], a1 = s[mf][1][i] + bvv[1];
                float a2 = s[mf][2][i] + bvv[2], a3 = s[mf][3][i] + bvv[3];
                s[mf][0][i] = a0; s[mf][1][i] = a1; s[mf][2][i] = a2; s[mf][3][i] = a3;
                rml[mf][i] = fmaxf(fmaxf(a0, a1), fmaxf(a2, a3));
            }
        bool need = false;
        #pragma unroll
        for (int mf = 0; mf < 2; ++mf)
            #pragma unroll
            for (int i = 0; i < 4; ++i)
                need = need || (rml[mf][i] > m_run[mf][i] + 8.f);

        if (__any(need)) {        // rare: full reduce + rescale
            #pragma unroll
            for (int off = 1; off < 16; off <<= 1)
                #pragma unroll
                for (int mf = 0; mf < 2; ++mf)
                    #pragma unroll
                    for (int i = 0; i < 4; ++i)
                        rml[mf][i] = fmaxf(rml[mf][i], __shfl_xor(rml[mf][i], off, 64));
            #pragma unroll
            for (int mf = 0; mf < 2; ++mf)
                #pragma unroll
                for (int i = 0; i < 4; ++i) {
                    const float mnew = fmaxf(m_run[mf][i], rml[mf][i]);
                    const float al = exp2_hw(m_run[mf][i] - mnew);
                    m_run[mf][i] = mnew;
                    ofl[mf][i] *= al;
                    #pragma unroll
                    for (int dt = 0; dt < 4; ++dt) of[mf][dt][i] *= al;
                }
        }

        // ---- prefetch bias(t+1) (guarded: buffer ends exactly) ----
        bp += (it < 31) ? 64 : 0;
        #pragma unroll
        for (int nt = 0; nt < 4; ++nt) bvv[nt] = bp[nt * 16] * 1.44269504f;

        // ---- P = exp2(S - m) -> wave-private LDS ----
        #pragma unroll
        for (int mf = 0; mf < 2; ++mf)
            #pragma unroll
            for (int nt = 0; nt < 4; ++nt)
                #pragma unroll
                for (int i = 0; i < 4; ++i) {
                    const float p = exp2_hw(s[mf][nt][i] - m_run[mf][i]);
                    Ps[w][mf * 16 + lg * 4 + i][nt * 16 + lr] = (bf16)p;
                }

        // ---- O += P V ; l += P * ones ----
        bf16x8 pa[2][2];
        #pragma unroll
        for (int mf = 0; mf < 2; ++mf)
            #pragma unroll
            for (int ks = 0; ks < 2; ++ks)
                pa[mf][ks] = *(const bf16x8*)&Ps[w][mf * 16 + lr][ks * 32 + lg * 8];

        __builtin_amdgcn_s_setprio(1);
        #pragma unroll
        for (int mf = 0; mf < 2; ++mf)
            #pragma unroll
            for (int ks = 0; ks < 2; ++ks) {
                #pragma unroll
                for (int dt = 0; dt < 4; ++dt)
                    of[mf][dt] = MFMA16(pa[mf][ks], vf[ks][dt], of[mf][dt]);
                ofl[mf] = MFMA16(pa[mf][ks], ones8, ofl[mf]);
            }
        __builtin_amdgcn_s_setprio(0);

        __builtin_amdgcn_sched_barrier(0);
        __builtin_amdgcn_s_barrier();              // all waves done with cur
    }

    // ---- finalize: O / l ----
    #pragma unroll
    for (int mf = 0; mf < 2; ++mf) {
        const size_t ob = (size_t)(b * 2048 + qrow + mf * 16 + lg * 4) * 1024 + h * 64;
        #pragma unroll
        for (int i = 0; i < 4; ++i) {
            const float inv = 1.0f / ofl[mf][i];
            #pragma unroll
            for (int dt = 0; dt < 4; ++dt)
                Oout[ob + (size_t)i * 1024 + dt * 16 + lr] = (bf16)(of[mf][dt][i] * inv);
        }
    }
}

// ---------------------------------------------------------------------------
extern "C" void kernel_launch(void* const* d_in, const int* in_sizes, int n_in,
                              void* d_out, int out_size, void* d_ws, size_t ws_size,
                              hipStream_t stream) {
    const float* query  = (const float*)d_in[0];
    const float* memory = (const float*)d_in[1];
    const float* mbias  = (const float*)d_in[2];
    const float* Wq = (const float*)d_in[3];
    const float* bq = (const float*)d_in[4];
    const float* Wk = (const float*)d_in[5];
    const float* bk = (const float*)d_in[6];
    const float* Wv = (const float*)d_in[7];
    const float* bv = (const float*)d_in[8];
    const float* Wo = (const float*)d_in[9];
    const float* bo = (const float*)d_in[10];
    float* out = (float*)d_out;

    const size_t SZ = 4096ull * 1024ull * sizeof(bf16);   // 8 MiB
    const size_t WZ = 1024ull * 1024ull * sizeof(bf16);   // 2 MiB
    char* ws = (char*)d_ws;
    bf16* Qp  = (bf16*)(ws);
    bf16* Kp  = (bf16*)(ws + SZ);       // also query_bf16 staging
    bf16* Vtp = (bf16*)(ws + 2 * SZ);
    bf16* Ap  = (bf16*)(ws + 3 * SZ);   // also memory_bf16 staging
    bf16* WTq = (bf16*)(ws + 4 * SZ);
    bf16* WTk = (bf16*)(ws + 4 * SZ + WZ);
    bf16* WTv = (bf16*)(ws + 4 * SZ + 2 * WZ);
    bf16* WTo = (bf16*)(ws + 4 * SZ + 3 * WZ);

    dim3 blk(256);
    cvt_kernel<<<dim3(2048, 2), blk, 0, stream>>>(query, memory, Kp, Ap);
    transpose_cvt_kernel<<<dim3(16, 16, 4), blk, 0, stream>>>(
        Wq, Wk, Wv, Wo, WTq, WTk, WTv, WTo);

    dim3 gg(16, 32);
    // Q scaled by DH^-0.5 * log2(e): softmax runs in exp2 domain.
    gemm_kernel<bf16><<<gg, blk, 0, stream>>>(Kp, WTq, bq, Qp,  0.18033688f, 0);
    gemm_kernel<bf16><<<gg, blk, 0, stream>>>(Ap, WTk, bk, Kp,  1.0f, 0);
    gemm_kernel<bf16><<<gg, blk, 0, stream>>>(Ap, WTv, bv, Vtp, 1.0f, 1);
    attn_kernel<<<dim3(16, 16, 2), blk, 0, stream>>>(Qp, Kp, Vtp, mbias, Ap);
    gemm_kernel<float><<<gg, blk, 0, stream>>>(Ap, WTo, bo, out, 1.0f, 0);
}

// Round 8
// 150.136 us; speedup vs baseline: 2.2093x; 1.0644x over previous
//
#include <hip/hip_runtime.h>
#include <hip/hip_bf16.h>
#include <math.h>

// B=2, LQ=LM=2048, D=1024, H=16, DH=64. f32 I/O, bf16 MFMA internal.
// cvt(acts) + transpose(weights) -> QKV GEMMs (dbuf 2-phase global_load_lds) ->
// flash attn (8-wave blocks, LDS K/V staging, counted vmcnt) -> out GEMM.

typedef __bf16 bf16;
typedef __bf16 bf16x4 __attribute__((ext_vector_type(4)));
typedef __bf16 bf16x8 __attribute__((ext_vector_type(8)));
typedef float f32x4 __attribute__((ext_vector_type(4)));

#define MFMA16(a, b, c) __builtin_amdgcn_mfma_f32_16x16x32_bf16((a), (b), (c), 0, 0, 0)

__device__ inline float exp2_hw(float x) {
    float r; asm("v_exp_f32 %0, %1" : "=v"(r) : "v"(x)); return r;   // 2^x
}

__device__ inline void gload_lds16(const bf16* g, bf16* l) {
    __builtin_amdgcn_global_load_lds(
        (const __attribute__((address_space(1))) void*)g,
        (__attribute__((address_space(3))) void*)l, 16, 0, 0);
}

// ---------------------------------------------------------------------------
// Activations f32 -> bf16. Grid (2048, 2), 8 elems/thread.
// ---------------------------------------------------------------------------
__global__ __launch_bounds__(256) void cvt_kernel(
    const float* __restrict__ X0, const float* __restrict__ X1,
    bf16* __restrict__ Y0, bf16* __restrict__ Y1)
{
    const float* X = blockIdx.y ? X1 : X0;
    bf16* Y = blockIdx.y ? Y1 : Y0;
    const size_t i = ((size_t)blockIdx.x * 256 + threadIdx.x) * 8;
    float4 f0 = *(const float4*)&X[i];
    float4 f1 = *(const float4*)&X[i + 4];
    bf16x8 h;
    h[0] = (bf16)f0.x; h[1] = (bf16)f0.y; h[2] = (bf16)f0.z; h[3] = (bf16)f0.w;
    h[4] = (bf16)f1.x; h[5] = (bf16)f1.y; h[6] = (bf16)f1.z; h[7] = (bf16)f1.w;
    *(bf16x8*)&Y[i] = h;
}

// ---------------------------------------------------------------------------
// Weight transpose + f32->bf16: WT[n][k] = (bf16)W[k][n], 1024x1024 each.
// ---------------------------------------------------------------------------
__global__ __launch_bounds__(256) void transpose_cvt_kernel(
    const float* __restrict__ W0, const float* __restrict__ W1,
    const float* __restrict__ W2, const float* __restrict__ W3,
    bf16* __restrict__ T0, bf16* __restrict__ T1,
    bf16* __restrict__ T2, bf16* __restrict__ T3)
{
    __shared__ float Ls[64][65];
    const float* W; bf16* T;
    switch (blockIdx.z) {
        case 0:  W = W0; T = T0; break;
        case 1:  W = W1; T = T1; break;
        case 2:  W = W2; T = T2; break;
        default: W = W3; T = T3; break;
    }
    const int t = threadIdx.x;
    const int n0 = blockIdx.x * 64, k0 = blockIdx.y * 64;
    const int g = t >> 4, c = (t & 15) * 4;

    #pragma unroll
    for (int p = 0; p < 4; ++p) {
        const int row = p * 16 + g;
        float4 f = *(const float4*)&W[(size_t)(k0 + row) * 1024 + n0 + c];
        Ls[row][c + 0] = f.x; Ls[row][c + 1] = f.y;
        Ls[row][c + 2] = f.z; Ls[row][c + 3] = f.w;
    }
    __syncthreads();
    #pragma unroll
    for (int p = 0; p < 4; ++p) {
        const int n = p * 16 + g;
        bf16x4 h;
        h[0] = (bf16)Ls[c + 0][n]; h[1] = (bf16)Ls[c + 1][n];
        h[2] = (bf16)Ls[c + 2][n]; h[3] = (bf16)Ls[c + 3][n];
        *(bf16x4*)&T[(size_t)(n0 + n) * 1024 + k0 + c] = h;
    }
}

// ---------------------------------------------------------------------------
// GEMM: out = (A[M,1024](bf16) @ W + bias) * alpha, W as WT[n][k] bf16.
// BM=128, BN=64, BK=64; grid (16,32)=512 blocks. Double-buffered 2-phase:
// issue stage(t+1) at iter top, compute tile t, one __syncthreads drain.
// ---------------------------------------------------------------------------
template <typename TO>
__global__ __launch_bounds__(256) void gemm_kernel(
    const bf16* __restrict__ A, const bf16* __restrict__ WT,
    const float* __restrict__ bias, TO* __restrict__ out,
    float alpha, int mode)
{
    __shared__ __align__(16) bf16 As[2][128 * 64];
    __shared__ __align__(16) bf16 Bs[2][64 * 64];

    const int fid = blockIdx.x + (blockIdx.y << 4);
    const int swz = (fid & 7) * 64 + (fid >> 3);
    const int n0 = (swz & 15) * 64;
    const int m0 = (swz >> 4) * 128;

    const int tid = threadIdx.x;
    const int w = tid >> 6, lane = tid & 63;
    const int lr = lane & 15, lg = lane >> 4;
    const int wm = (w >> 1) * 64, wn = (w & 1) * 32;

    const int arow0 = w * 32 + (lane >> 3);
    const int brow0 = w * 16 + (lane >> 3);
    const int sch = lane & 7;

    f32x4 acc[4][2] = {};

    auto stageG = [&](int kt, int bi) {
        #pragma unroll
        for (int p = 0; p < 4; ++p) {
            const int row = arow0 + p * 8;
            const int xc = ((sch ^ (row & 7)) << 3);
            gload_lds16(&A[(size_t)(m0 + row) * 1024 + kt + xc],
                        &As[bi][row * 64 + sch * 8]);
        }
        #pragma unroll
        for (int p = 0; p < 2; ++p) {
            const int row = brow0 + p * 8;
            const int xc = ((sch ^ (row & 7)) << 3);
            gload_lds16(&WT[(size_t)(n0 + row) * 1024 + kt + xc],
                        &Bs[bi][row * 64 + sch * 8]);
        }
    };

    stageG(0, 0);
    __syncthreads();

    int cur = 0;
    #pragma unroll 1
    for (int t = 0; t < 16; ++t) {
        if (t < 15) stageG((t + 1) * 64, cur ^ 1);   // async: lands by next sync

        #pragma unroll
        for (int ks = 0; ks < 2; ++ks) {
            const int c = (((ks * 4 + lg) ^ (lr & 7)) << 3);
            bf16x8 af[4], bfv[2];
            #pragma unroll
            for (int mt = 0; mt < 4; ++mt)
                af[mt] = *(const bf16x8*)&As[cur][(wm + mt * 16 + lr) * 64 + c];
            #pragma unroll
            for (int nt = 0; nt < 2; ++nt)
                bfv[nt] = *(const bf16x8*)&Bs[cur][(wn + nt * 16 + lr) * 64 + c];
            #pragma unroll
            for (int nt = 0; nt < 2; ++nt)
                #pragma unroll
                for (int mt = 0; mt < 4; ++mt)
                    acc[mt][nt] = MFMA16(af[mt], bfv[nt], acc[mt][nt]);
        }
        __syncthreads();      // drains vmcnt (stage t+1 landed) + lgkm; reuse safe
        cur ^= 1;
    }

    #pragma unroll
    for (int nt = 0; nt < 2; ++nt) {
        const int n = n0 + wn + nt * 16 + lr;
        const float bv = bias[n];
        #pragma unroll
        for (int mt = 0; mt < 4; ++mt) {
            #pragma unroll
            for (int i = 0; i < 4; ++i) {
                const int m = m0 + wm + mt * 16 + lg * 4 + i;
                const float v = (acc[mt][nt][i] + bv) * alpha;
                if (mode == 0) {
                    out[(size_t)m * 1024 + n] = (TO)v;
                } else {
                    const int b = m >> 11, t2 = m & 2047;
                    out[((size_t)(b << 10) + n) * 2048 + t2] = (TO)v;
                }
            }
        }
    }
}

// ---------------------------------------------------------------------------
// Flash attention v5. Grid (16,16,2)=512 blocks, 8 waves x 16 q-rows (512 thr,
// 4 waves/SIMD target). K/V double-buffered LDS staging (2 gload/wave/tile,
// counted vmcnt(2)). Bias folded into S accumulator init. Defer-max softmax,
// l via ones-MFMA, log2-domain exp, wave-private P.
// ---------------------------------------------------------------------------
__global__ __launch_bounds__(512, 4) void attn_kernel(
    const bf16* __restrict__ Q, const bf16* __restrict__ K,
    const bf16* __restrict__ Vt, const float* __restrict__ mbias,
    bf16* __restrict__ Oout)
{
    __shared__ __align__(16) bf16 Kbuf[2][4096];   // 64 keys x 64 d, swizzled
    __shared__ __align__(16) bf16 Vbuf[2][4096];   // 64 d x 64 keys, swizzled
    __shared__ bf16 Ps[8][16][76];                 // wave-private P

    const int tid = threadIdx.x;
    const int w = tid >> 6, lane = tid & 63;
    const int lr = lane & 15, lg = lane >> 4;

    // XCD swizzle: each XCD -> 4 (h,b) groups (2MB K+V, L2-resident)
    const int fid = blockIdx.x + (blockIdx.y << 4) + (blockIdx.z << 8);
    const int swz = (fid & 7) * 64 + (fid >> 3);
    const int qt = swz & 15, h = (swz >> 4) & 15, b = swz >> 8;
    const int qrow = qt * 128 + w * 16;

    const size_t qo = (size_t)(b * 2048 + qrow + lr) * 1024 + h * 64;
    bf16x8 qf[2];
    qf[0] = *(const bf16x8*)&Q[qo + lg * 8];
    qf[1] = *(const bf16x8*)&Q[qo + 32 + lg * 8];

    const bf16* Kb = K + (size_t)b * 2048 * 1024 + h * 64;
    const bf16* Vb = Vt + ((size_t)b * 1024 + h * 64) * 2048;
    const float* bp = mbias + b * 2048 + lr;

    float m_run[4];
    f32x4 of[4] = {};
    f32x4 ofl = {};
    #pragma unroll
    for (int i = 0; i < 4; ++i) m_run[i] = -INFINITY;

    bf16x8 ones8;
    #pragma unroll
    for (int j = 0; j < 8; ++j) ones8[j] = (bf16)1.0f;

    // stage tile t: 512 16B chunks K + 512 V over 8 waves -> 2 gload per wave.
    // LDS dest linear; SOURCE chunk XOR-swizzled (rule 21).
    const int chunk = w * 64 + lane;               // 0..511
    const int sR = chunk >> 3, scs = (chunk & 7) ^ (sR & 7);
    auto stage = [&](int t, int bi) {
        gload_lds16(Kb + (size_t)(t * 64 + sR) * 1024 + scs * 8,
                    &Kbuf[bi][chunk * 8]);
        gload_lds16(Vb + (size_t)sR * 2048 + t * 64 + scs * 8,
                    &Vbuf[bi][chunk * 8]);
    };

    stage(0, 0);
    float bvv[4];
    #pragma unroll
    for (int nt = 0; nt < 4; ++nt) bvv[nt] = bp[nt * 16] * 1.44269504f;

    #pragma unroll 1
    for (int it = 0; it < 32; ++it) {
        const int cur = it & 1;
        stage(it < 31 ? it + 1 : 31, cur ^ 1);     // async prefetch next tile
        asm volatile("s_waitcnt vmcnt(2)" ::: "memory");  // cur's stage landed
        __builtin_amdgcn_s_barrier();
        __builtin_amdgcn_sched_barrier(0);

        // ---- S = bias + Q K^T (bias in accumulator init) ----
        f32x4 s[4];
        #pragma unroll
        for (int nt = 0; nt < 4; ++nt) {
            s[nt][0] = bvv[nt]; s[nt][1] = bvv[nt];
            s[nt][2] = bvv[nt]; s[nt][3] = bvv[nt];
        }
        #pragma unroll
        for (int ks = 0; ks < 2; ++ks) {
            const int cw = (((ks * 4 + lg) ^ (lr & 7)) << 3);
            bf16x8 kf[4];
            #pragma unroll
            for (int nt = 0; nt < 4; ++nt)
                kf[nt] = *(const bf16x8*)&Kbuf[cur][(nt * 16 + lr) * 64 + cw];
            __builtin_amdgcn_s_setprio(1);
            #pragma unroll
            for (int nt = 0; nt < 4; ++nt)
                s[nt] = MFMA16(qf[ks], kf[nt], s[nt]);
            __builtin_amdgcn_s_setprio(0);
        }

        // ---- in-lane row max; defer-max check ----
        float rml[4];
        #pragma unroll
        for (int i = 0; i < 4; ++i)
            rml[i] = fmaxf(fmaxf(s[0][i], s[1][i]), fmaxf(s[2][i], s[3][i]));
        bool need = false;
        #pragma unroll
        for (int i = 0; i < 4; ++i)
            need = need || (rml[i] > m_run[i] + 8.f);

        if (__any(need)) {        // rare: full reduce + rescale
            #pragma unroll
            for (int off = 1; off < 16; off <<= 1)
                #pragma unroll
                for (int i = 0; i < 4; ++i)
                    rml[i] = fmaxf(rml[i], __shfl_xor(rml[i], off, 64));
            #pragma unroll
            for (int i = 0; i < 4; ++i) {
                const float mnew = fmaxf(m_run[i], rml[i]);
                const float al = exp2_hw(m_run[i] - mnew);
                m_run[i] = mnew;
                ofl[i] *= al;
                #pragma unroll
                for (int dt = 0; dt < 4; ++dt) of[dt][i] *= al;
            }
        }

        // ---- prefetch bias(t+1) ----
        bp += (it < 31) ? 64 : 0;
        #pragma unroll
        for (int nt = 0; nt < 4; ++nt) bvv[nt] = bp[nt * 16] * 1.44269504f;

        // ---- P = exp2(S - m) -> wave-private LDS ----
        #pragma unroll
        for (int nt = 0; nt < 4; ++nt)
            #pragma unroll
            for (int i = 0; i < 4; ++i) {
                const float p = exp2_hw(s[nt][i] - m_run[i]);
                Ps[w][lg * 4 + i][nt * 16 + lr] = (bf16)p;
            }

        // ---- V fragments + O += P V ; l += P * ones ----
        bf16x8 vf[2][4];
        #pragma unroll
        for (int ks = 0; ks < 2; ++ks) {
            const int cw = (((ks * 4 + lg) ^ (lr & 7)) << 3);
            #pragma unroll
            for (int dt = 0; dt < 4; ++dt)
                vf[ks][dt] = *(const bf16x8*)&Vbuf[cur][(dt * 16 + lr) * 64 + cw];
        }
        bf16x8 pa0 = *(const bf16x8*)&Ps[w][lr][lg * 8];
        bf16x8 pa1 = *(const bf16x8*)&Ps[w][lr][32 + lg * 8];
        __builtin_amdgcn_s_setprio(1);
        #pragma unroll
        for (int dt = 0; dt < 4; ++dt) of[dt] = MFMA16(pa0, vf[0][dt], of[dt]);
        ofl = MFMA16(pa0, ones8, ofl);
        #pragma unroll
        for (int dt = 0; dt < 4; ++dt) of[dt] = MFMA16(pa1, vf[1][dt], of[dt]);
        ofl = MFMA16(pa1, ones8, ofl);
        __builtin_amdgcn_s_setprio(0);

        __builtin_amdgcn_sched_barrier(0);
        __builtin_amdgcn_s_barrier();              // all waves done with cur
    }

    // ---- finalize: O / l ----
    const size_t ob = (size_t)(b * 2048 + qrow + lg * 4) * 1024 + h * 64;
    #pragma unroll
    for (int i = 0; i < 4; ++i) {
        const float inv = 1.0f / ofl[i];
        #pragma unroll
        for (int dt = 0; dt < 4; ++dt)
            Oout[ob + (size_t)i * 1024 + dt * 16 + lr] = (bf16)(of[dt][i] * inv);
    }
}

// ---------------------------------------------------------------------------
extern "C" void kernel_launch(void* const* d_in, const int* in_sizes, int n_in,
                              void* d_out, int out_size, void* d_ws, size_t ws_size,
                              hipStream_t stream) {
    const float* query  = (const float*)d_in[0];
    const float* memory = (const float*)d_in[1];
    const float* mbias  = (const float*)d_in[2];
    const float* Wq = (const float*)d_in[3];
    const float* bq = (const float*)d_in[4];
    const float* Wk = (const float*)d_in[5];
    const float* bk = (const float*)d_in[6];
    const float* Wv = (const float*)d_in[7];
    const float* bv = (const float*)d_in[8];
    const float* Wo = (const float*)d_in[9];
    const float* bo = (const float*)d_in[10];
    float* out = (float*)d_out;

    const size_t SZ = 4096ull * 1024ull * sizeof(bf16);   // 8 MiB
    const size_t WZ = 1024ull * 1024ull * sizeof(bf16);   // 2 MiB
    char* ws = (char*)d_ws;
    bf16* Qp  = (bf16*)(ws);
    bf16* Kp  = (bf16*)(ws + SZ);       // also query_bf16 staging
    bf16* Vtp = (bf16*)(ws + 2 * SZ);
    bf16* Ap  = (bf16*)(ws + 3 * SZ);   // also memory_bf16 staging
    bf16* WTq = (bf16*)(ws + 4 * SZ);
    bf16* WTk = (bf16*)(ws + 4 * SZ + WZ);
    bf16* WTv = (bf16*)(ws + 4 * SZ + 2 * WZ);
    bf16* WTo = (bf16*)(ws + 4 * SZ + 3 * WZ);

    dim3 blk(256);
    cvt_kernel<<<dim3(2048, 2), blk, 0, stream>>>(query, memory, Kp, Ap);
    transpose_cvt_kernel<<<dim3(16, 16, 4), blk, 0, stream>>>(
        Wq, Wk, Wv, Wo, WTq, WTk, WTv, WTo);

    dim3 gg(16, 32);
    // Q scaled by DH^-0.5 * log2(e): softmax runs in exp2 domain.
    gemm_kernel<bf16><<<gg, blk, 0, stream>>>(Kp, WTq, bq, Qp,  0.18033688f, 0);
    gemm_kernel<bf16><<<gg, blk, 0, stream>>>(Ap, WTk, bk, Kp,  1.0f, 0);
    gemm_kernel<bf16><<<gg, blk, 0, stream>>>(Ap, WTv, bv, Vtp, 1.0f, 1);
    attn_kernel<<<dim3(16, 16, 2), dim3(512), 0, stream>>>(Qp, Kp, Vtp, mbias, Ap);
    gemm_kernel<float><<<gg, blk, 0, stream>>>(Ap, WTo, bo, out, 1.0f, 0);
}

// Round 9
// 125.027 us; speedup vs baseline: 2.6530x; 1.2008x over previous
//
#include <hip/hip_runtime.h>
#include <hip/hip_bf16.h>
#include <math.h>

// B=2, LQ=LM=2048, D=1024, H=16, DH=64. f32 I/O, bf16 MFMA internal.
// cvt + transpose -> Q GEMM + fused KV GEMM -> flash attn (swapped QK^T,
// lane-local P, 4-slot LDS, 1 barrier/iter) -> out GEMM.

typedef __bf16 bf16;
typedef __bf16 bf16x4 __attribute__((ext_vector_type(4)));
typedef __bf16 bf16x8 __attribute__((ext_vector_type(8)));
typedef float f32x4 __attribute__((ext_vector_type(4)));

#define MFMA16(a, b, c) __builtin_amdgcn_mfma_f32_16x16x32_bf16((a), (b), (c), 0, 0, 0)

__device__ inline float exp2_hw(float x) {
    float r; asm("v_exp_f32 %0, %1" : "=v"(r) : "v"(x)); return r;   // 2^x
}

__device__ inline void gload_lds16(const bf16* g, bf16* l) {
    __builtin_amdgcn_global_load_lds(
        (const __attribute__((address_space(1))) void*)g,
        (__attribute__((address_space(3))) void*)l, 16, 0, 0);
}

// ---------------------------------------------------------------------------
// Activations f32 -> bf16. Grid (2048, 2), 8 elems/thread.
// ---------------------------------------------------------------------------
__global__ __launch_bounds__(256) void cvt_kernel(
    const float* __restrict__ X0, const float* __restrict__ X1,
    bf16* __restrict__ Y0, bf16* __restrict__ Y1)
{
    const float* X = blockIdx.y ? X1 : X0;
    bf16* Y = blockIdx.y ? Y1 : Y0;
    const size_t i = ((size_t)blockIdx.x * 256 + threadIdx.x) * 8;
    float4 f0 = *(const float4*)&X[i];
    float4 f1 = *(const float4*)&X[i + 4];
    bf16x8 h;
    h[0] = (bf16)f0.x; h[1] = (bf16)f0.y; h[2] = (bf16)f0.z; h[3] = (bf16)f0.w;
    h[4] = (bf16)f1.x; h[5] = (bf16)f1.y; h[6] = (bf16)f1.z; h[7] = (bf16)f1.w;
    *(bf16x8*)&Y[i] = h;
}

// ---------------------------------------------------------------------------
// Weight transpose + f32->bf16: WT[n][k] = (bf16)W[k][n], 1024x1024 each.
// ---------------------------------------------------------------------------
__global__ __launch_bounds__(256) void transpose_cvt_kernel(
    const float* __restrict__ W0, const float* __restrict__ W1,
    const float* __restrict__ W2, const float* __restrict__ W3,
    bf16* __restrict__ T0, bf16* __restrict__ T1,
    bf16* __restrict__ T2, bf16* __restrict__ T3)
{
    __shared__ float Ls[64][65];
    const float* W; bf16* T;
    switch (blockIdx.z) {
        case 0:  W = W0; T = T0; break;
        case 1:  W = W1; T = T1; break;
        case 2:  W = W2; T = T2; break;
        default: W = W3; T = T3; break;
    }
    const int t = threadIdx.x;
    const int n0 = blockIdx.x * 64, k0 = blockIdx.y * 64;
    const int g = t >> 4, c = (t & 15) * 4;

    #pragma unroll
    for (int p = 0; p < 4; ++p) {
        const int row = p * 16 + g;
        float4 f = *(const float4*)&W[(size_t)(k0 + row) * 1024 + n0 + c];
        Ls[row][c + 0] = f.x; Ls[row][c + 1] = f.y;
        Ls[row][c + 2] = f.z; Ls[row][c + 3] = f.w;
    }
    __syncthreads();
    #pragma unroll
    for (int p = 0; p < 4; ++p) {
        const int n = p * 16 + g;
        bf16x4 h;
        h[0] = (bf16)Ls[c + 0][n]; h[1] = (bf16)Ls[c + 1][n];
        h[2] = (bf16)Ls[c + 2][n]; h[3] = (bf16)Ls[c + 3][n];
        *(bf16x4*)&T[(size_t)(n0 + n) * 1024 + k0 + c] = h;
    }
}

// ---------------------------------------------------------------------------
// GEMM: out = (A[M,1024](bf16) @ W + bias) * alpha, W as WT[n][k] bf16.
// BM=128, BN=64, BK=64; grid (16,32)=512. 2-phase dbuf global_load_lds.
// ---------------------------------------------------------------------------
template <typename TO>
__global__ __launch_bounds__(256) void gemm_kernel(
    const bf16* __restrict__ A, const bf16* __restrict__ WT,
    const float* __restrict__ bias, TO* __restrict__ out,
    float alpha, int mode)
{
    __shared__ __align__(16) bf16 As[2][128 * 64];
    __shared__ __align__(16) bf16 Bs[2][64 * 64];

    const int fid = blockIdx.x + (blockIdx.y << 4);
    const int swz = (fid & 7) * 64 + (fid >> 3);
    const int n0 = (swz & 15) * 64;
    const int m0 = (swz >> 4) * 128;

    const int tid = threadIdx.x;
    const int w = tid >> 6, lane = tid & 63;
    const int lr = lane & 15, lg = lane >> 4;
    const int wm = (w >> 1) * 64, wn = (w & 1) * 32;

    const int arow0 = w * 32 + (lane >> 3);
    const int brow0 = w * 16 + (lane >> 3);
    const int sch = lane & 7;

    f32x4 acc[4][2] = {};

    auto stageG = [&](int kt, int bi) {
        #pragma unroll
        for (int p = 0; p < 4; ++p) {
            const int row = arow0 + p * 8;
            const int xc = ((sch ^ (row & 7)) << 3);
            gload_lds16(&A[(size_t)(m0 + row) * 1024 + kt + xc],
                        &As[bi][row * 64 + sch * 8]);
        }
        #pragma unroll
        for (int p = 0; p < 2; ++p) {
            const int row = brow0 + p * 8;
            const int xc = ((sch ^ (row & 7)) << 3);
            gload_lds16(&WT[(size_t)(n0 + row) * 1024 + kt + xc],
                        &Bs[bi][row * 64 + sch * 8]);
        }
    };

    stageG(0, 0);
    __syncthreads();

    int cur = 0;
    #pragma unroll 1
    for (int t = 0; t < 16; ++t) {
        if (t < 15) stageG((t + 1) * 64, cur ^ 1);

        #pragma unroll
        for (int ks = 0; ks < 2; ++ks) {
            const int c = (((ks * 4 + lg) ^ (lr & 7)) << 3);
            bf16x8 af[4], bfv[2];
            #pragma unroll
            for (int mt = 0; mt < 4; ++mt)
                af[mt] = *(const bf16x8*)&As[cur][(wm + mt * 16 + lr) * 64 + c];
            #pragma unroll
            for (int nt = 0; nt < 2; ++nt)
                bfv[nt] = *(const bf16x8*)&Bs[cur][(wn + nt * 16 + lr) * 64 + c];
            #pragma unroll
            for (int nt = 0; nt < 2; ++nt)
                #pragma unroll
                for (int mt = 0; mt < 4; ++mt)
                    acc[mt][nt] = MFMA16(af[mt], bfv[nt], acc[mt][nt]);
        }
        __syncthreads();
        cur ^= 1;
    }

    #pragma unroll
    for (int nt = 0; nt < 2; ++nt) {
        const int n = n0 + wn + nt * 16 + lr;
        const float bv = bias[n];
        #pragma unroll
        for (int mt = 0; mt < 4; ++mt) {
            #pragma unroll
            for (int i = 0; i < 4; ++i) {
                const int m = m0 + wm + mt * 16 + lg * 4 + i;
                const float v = (acc[mt][nt][i] + bv) * alpha;
                if (mode == 0) {
                    out[(size_t)m * 1024 + n] = (TO)v;
                } else {
                    const int b = m >> 11, t2 = m & 2047;
                    out[((size_t)(b << 10) + n) * 2048 + t2] = (TO)v;
                }
            }
        }
    }
}

// ---------------------------------------------------------------------------
// Fused K+V GEMM: stages A (memory) once, both WTk/WTv B-tiles.
// K -> row-major [B*LM,1024]; V -> per-batch transposed [b][n][t].
// ---------------------------------------------------------------------------
__global__ __launch_bounds__(256) void gemm_kv_kernel(
    const bf16* __restrict__ A, const bf16* __restrict__ WTk,
    const bf16* __restrict__ WTv, const float* __restrict__ bk,
    const float* __restrict__ bv, bf16* __restrict__ Kout,
    bf16* __restrict__ Vtout)
{
    __shared__ __align__(16) bf16 As[2][128 * 64];
    __shared__ __align__(16) bf16 Bk[2][64 * 64];
    __shared__ __align__(16) bf16 Bv[2][64 * 64];

    const int fid = blockIdx.x + (blockIdx.y << 4);
    const int swz = (fid & 7) * 64 + (fid >> 3);
    const int n0 = (swz & 15) * 64;
    const int m0 = (swz >> 4) * 128;

    const int tid = threadIdx.x;
    const int w = tid >> 6, lane = tid & 63;
    const int lr = lane & 15, lg = lane >> 4;
    const int wm = (w >> 1) * 64, wn = (w & 1) * 32;

    const int arow0 = w * 32 + (lane >> 3);
    const int brow0 = w * 16 + (lane >> 3);
    const int sch = lane & 7;

    f32x4 accK[4][2] = {}, accV[4][2] = {};

    auto stageG = [&](int kt, int bi) {
        #pragma unroll
        for (int p = 0; p < 4; ++p) {
            const int row = arow0 + p * 8;
            const int xc = ((sch ^ (row & 7)) << 3);
            gload_lds16(&A[(size_t)(m0 + row) * 1024 + kt + xc],
                        &As[bi][row * 64 + sch * 8]);
        }
        #pragma unroll
        for (int p = 0; p < 2; ++p) {
            const int row = brow0 + p * 8;
            const int xc = ((sch ^ (row & 7)) << 3);
            gload_lds16(&WTk[(size_t)(n0 + row) * 1024 + kt + xc],
                        &Bk[bi][row * 64 + sch * 8]);
            gload_lds16(&WTv[(size_t)(n0 + row) * 1024 + kt + xc],
                        &Bv[bi][row * 64 + sch * 8]);
        }
    };

    stageG(0, 0);
    __syncthreads();

    int cur = 0;
    #pragma unroll 1
    for (int t = 0; t < 16; ++t) {
        if (t < 15) stageG((t + 1) * 64, cur ^ 1);

        #pragma unroll
        for (int ks = 0; ks < 2; ++ks) {
            const int c = (((ks * 4 + lg) ^ (lr & 7)) << 3);
            bf16x8 af[4], bkf[2], bvf[2];
            #pragma unroll
            for (int mt = 0; mt < 4; ++mt)
                af[mt] = *(const bf16x8*)&As[cur][(wm + mt * 16 + lr) * 64 + c];
            #pragma unroll
            for (int nt = 0; nt < 2; ++nt) {
                bkf[nt] = *(const bf16x8*)&Bk[cur][(wn + nt * 16 + lr) * 64 + c];
                bvf[nt] = *(const bf16x8*)&Bv[cur][(wn + nt * 16 + lr) * 64 + c];
            }
            #pragma unroll
            for (int nt = 0; nt < 2; ++nt)
                #pragma unroll
                for (int mt = 0; mt < 4; ++mt) {
                    accK[mt][nt] = MFMA16(af[mt], bkf[nt], accK[mt][nt]);
                    accV[mt][nt] = MFMA16(af[mt], bvf[nt], accV[mt][nt]);
                }
        }
        __syncthreads();
        cur ^= 1;
    }

    #pragma unroll
    for (int nt = 0; nt < 2; ++nt) {
        const int n = n0 + wn + nt * 16 + lr;
        const float bkv = bk[n], bvv = bv[n];
        #pragma unroll
        for (int mt = 0; mt < 4; ++mt) {
            #pragma unroll
            for (int i = 0; i < 4; ++i) {
                const int m = m0 + wm + mt * 16 + lg * 4 + i;
                Kout[(size_t)m * 1024 + n] = (bf16)(accK[mt][nt][i] + bkv);
                const int b = m >> 11, t2 = m & 2047;
                Vtout[((size_t)(b << 10) + n) * 2048 + t2] = (bf16)(accV[mt][nt][i] + bvv);
            }
        }
    }
}

// ---------------------------------------------------------------------------
// Flash attention v6: swapped QK^T (S^T = K·Q^T) with key-permuted staging so
// the PV B-fragment (P^T) is lane-local: NO P LDS round-trip, no shuffles.
// Grid (16,16,2)=512 blocks, 8 waves x 16 q-rows. K/V 4-slot LDS, ONE
// s_barrier per iter (write-at-distance-4 vs read-at-distance-0 is separated
// by two barriers; per-wave vmcnt(4) before the barrier publishes tile t).
// Per-lane: q = lane&15; S keys at (nt,i) = 32(nt&1) + 8(lane>>4) + 4(nt>>1) + i.
// ---------------------------------------------------------------------------
__global__ __launch_bounds__(512, 4) void attn_kernel(
    const bf16* __restrict__ Q, const bf16* __restrict__ K,
    const bf16* __restrict__ Vt, const float* __restrict__ mbias,
    bf16* __restrict__ Oout)
{
    __shared__ __align__(16) bf16 Kbuf[4][4096];   // 64 keys x 64 d (pi-permuted rows)
    __shared__ __align__(16) bf16 Vbuf[4][4096];   // 64 d x 64 keys

    const int tid = threadIdx.x;
    const int w = tid >> 6, lane = tid & 63;
    const int lr = lane & 15, lg = lane >> 4;

    // XCD swizzle: each XCD -> 4 (h,b) groups (L2-resident K/V)
    const int fid = blockIdx.x + (blockIdx.y << 4) + (blockIdx.z << 8);
    const int swz = (fid & 7) * 64 + (fid >> 3);
    const int qt = swz & 15, head = (swz >> 4) & 15, b = swz >> 8;
    const int qrow = qt * 128 + w * 16;

    // Q as B-operand: col=lr -> q row qrow+lr; k = ks*32 + lg*8 + j (same load)
    const size_t qo = (size_t)(b * 2048 + qrow + lr) * 1024 + head * 64;
    bf16x8 qf[2];
    qf[0] = *(const bf16x8*)&Q[qo + lg * 8];
    qf[1] = *(const bf16x8*)&Q[qo + 32 + lg * 8];

    const bf16* Kb = K + (size_t)b * 2048 * 1024 + head * 64;
    const bf16* Vb = Vt + ((size_t)b * 1024 + head * 64) * 2048;
    const float* biasb = mbias + b * 2048;

    float m_run = -INFINITY;       // scalar: all of this lane's S share q=lr
    f32x4 of[4] = {};              // O^T[d=16dt+4lg+i][q=lr]
    f32x4 ofl = {};                // l[q=lr] (all 4 comps equal)

    bf16x8 ones8;
    #pragma unroll
    for (int j = 0; j < 8; ++j) ones8[j] = (bf16)1.0f;

    // staging: 512 chunks x 8 elems per tile per matrix; 1 K + 1 V chunk/thread.
    // K rows pi-permuted: LDS row R holds key pi(R) so D-layout keys are
    // lane-local for PV. pi(16nt+lr') = 32*nt0 + 8*(lr'>>2) + 4*nt1 + (lr'&3).
    const int chunk = w * 64 + lane;               // 0..511
    const int R = chunk >> 3, cc = chunk & 7;
    const int cs = cc ^ (R & 7);                   // source-side XOR swizzle
    const int piR = ((R & 16) << 1) | ((R & 12) << 1) | ((R & 32) >> 3) | (R & 3);
    auto stage = [&](int t, int slot) {
        gload_lds16(Kb + (size_t)(t * 64 + piR) * 1024 + cs * 8,
                    &Kbuf[slot][chunk * 8]);
        gload_lds16(Vb + (size_t)R * 2048 + t * 64 + cs * 8,
                    &Vbuf[slot][chunk * 8]);
    };

    stage(0, 0);
    stage(1, 1);

    // bias (log2e-scaled), key of (nt,i) = 32(nt&1) + 4(nt>>1) + 8lg + i
    const float L2E = 1.44269504f;
    f32x4 b4[4];
    b4[0] = *(const f32x4*)&biasb[8 * lg];
    b4[1] = *(const f32x4*)&biasb[32 + 8 * lg];
    b4[2] = *(const f32x4*)&biasb[4 + 8 * lg];
    b4[3] = *(const f32x4*)&biasb[36 + 8 * lg];
    #pragma unroll
    for (int nt = 0; nt < 4; ++nt) b4[nt] *= L2E;

    #pragma unroll 1
    for (int it = 0; it < 32; ++it) {
        const int slot = it & 3;
        const int tn = (it < 30) ? it + 2 : 31;    // keeps vmcnt accounting exact
        stage(tn, (it + 2) & 3);
        asm volatile("s_waitcnt vmcnt(4)" ::: "memory");   // tile `it` landed
        __builtin_amdgcn_s_barrier();
        __builtin_amdgcn_sched_barrier(0);

        // ---- S^T = bias + K Q^T ----
        f32x4 s[4];
        #pragma unroll
        for (int nt = 0; nt < 4; ++nt) s[nt] = b4[nt];
        #pragma unroll
        for (int ks = 0; ks < 2; ++ks) {
            const int cw = (((ks * 4 + lg) ^ (lr & 7)) << 3);
            bf16x8 kf[4];
            #pragma unroll
            for (int nt = 0; nt < 4; ++nt)
                kf[nt] = *(const bf16x8*)&Kbuf[slot][(nt * 16 + lr) * 64 + cw];
            __builtin_amdgcn_s_setprio(1);
            #pragma unroll
            for (int nt = 0; nt < 4; ++nt)
                s[nt] = MFMA16(kf[nt], qf[ks], s[nt]);
            __builtin_amdgcn_s_setprio(0);
        }

        // ---- prefetch bias(t+1) ----
        const int bt = (it < 31) ? (it + 1) * 64 : 31 * 64;
        f32x4 b4n[4];
        b4n[0] = *(const f32x4*)&biasb[bt + 8 * lg];
        b4n[1] = *(const f32x4*)&biasb[bt + 32 + 8 * lg];
        b4n[2] = *(const f32x4*)&biasb[bt + 4 + 8 * lg];
        b4n[3] = *(const f32x4*)&biasb[bt + 36 + 8 * lg];

        // ---- in-lane max over 16 keys; defer-max ----
        float rml = s[0][0];
        #pragma unroll
        for (int nt = 0; nt < 4; ++nt)
            #pragma unroll
            for (int i = 0; i < 4; ++i) rml = fmaxf(rml, s[nt][i]);

        if (__any(rml > m_run + 8.f)) {            // rare: reduce + rescale
            float mx = fmaxf(rml, __shfl_xor(rml, 16, 64));
            mx = fmaxf(mx, __shfl_xor(mx, 32, 64));
            const float mnew = fmaxf(m_run, mx);
            const float al = exp2_hw(m_run - mnew);
            m_run = mnew;
            ofl *= al;
            #pragma unroll
            for (int dt = 0; dt < 4; ++dt) of[dt] *= al;
        }

        // ---- P = exp2(S - m): directly into lane-local B-fragments ----
        // pb[ks][4h+i] = P^T[32ks + 8lg + 4h + i][lr], source s[2h+ks][i]
        bf16x8 pb0, pb1;
        #pragma unroll
        for (int i = 0; i < 4; ++i) {
            pb0[i]     = (bf16)exp2_hw(s[0][i] - m_run);
            pb1[i]     = (bf16)exp2_hw(s[1][i] - m_run);
            pb0[4 + i] = (bf16)exp2_hw(s[2][i] - m_run);
            pb1[4 + i] = (bf16)exp2_hw(s[3][i] - m_run);
        }

        // ---- O^T += V^T P^T ; l += 1·P^T ----
        __builtin_amdgcn_s_setprio(1);
        #pragma unroll
        for (int ks = 0; ks < 2; ++ks) {
            const int cw = (((ks * 4 + lg) ^ (lr & 7)) << 3);
            const bf16x8 pb = ks ? pb1 : pb0;
            bf16x8 vf[4];
            #pragma unroll
            for (int dt = 0; dt < 4; ++dt)
                vf[dt] = *(const bf16x8*)&Vbuf[slot][(dt * 16 + lr) * 64 + cw];
            #pragma unroll
            for (int dt = 0; dt < 4; ++dt)
                of[dt] = MFMA16(vf[dt], pb, of[dt]);
            ofl = MFMA16(ones8, pb, ofl);
        }
        __builtin_amdgcn_s_setprio(0);

        #pragma unroll
        for (int nt = 0; nt < 4; ++nt) b4[nt] = b4n[nt] * L2E;
    }

    // ---- finalize: O = O^T/l, 8B-packed stores (d contiguous per lane) ----
    const float inv = 1.0f / ofl[0];
    const size_t ob = (size_t)(b * 2048 + qrow + lr) * 1024 + head * 64;
    #pragma unroll
    for (int dt = 0; dt < 4; ++dt) {
        bf16x4 h4;
        #pragma unroll
        for (int i = 0; i < 4; ++i) h4[i] = (bf16)(of[dt][i] * inv);
        *(bf16x4*)&Oout[ob + dt * 16 + lg * 4] = h4;
    }
}

// ---------------------------------------------------------------------------
extern "C" void kernel_launch(void* const* d_in, const int* in_sizes, int n_in,
                              void* d_out, int out_size, void* d_ws, size_t ws_size,
                              hipStream_t stream) {
    const float* query  = (const float*)d_in[0];
    const float* memory = (const float*)d_in[1];
    const float* mbias  = (const float*)d_in[2];
    const float* Wq = (const float*)d_in[3];
    const float* bq = (const float*)d_in[4];
    const float* Wk = (const float*)d_in[5];
    const float* bk = (const float*)d_in[6];
    const float* Wv = (const float*)d_in[7];
    const float* bv = (const float*)d_in[8];
    const float* Wo = (const float*)d_in[9];
    const float* bo = (const float*)d_in[10];
    float* out = (float*)d_out;

    const size_t SZ = 4096ull * 1024ull * sizeof(bf16);   // 8 MiB
    const size_t WZ = 1024ull * 1024ull * sizeof(bf16);   // 2 MiB
    char* ws = (char*)d_ws;
    bf16* Qp  = (bf16*)(ws);
    bf16* Kp  = (bf16*)(ws + SZ);       // also query_bf16 staging
    bf16* Vtp = (bf16*)(ws + 2 * SZ);
    bf16* Ap  = (bf16*)(ws + 3 * SZ);   // also memory_bf16 staging
    bf16* WTq = (bf16*)(ws + 4 * SZ);
    bf16* WTk = (bf16*)(ws + 4 * SZ + WZ);
    bf16* WTv = (bf16*)(ws + 4 * SZ + 2 * WZ);
    bf16* WTo = (bf16*)(ws + 4 * SZ + 3 * WZ);

    dim3 blk(256);
    cvt_kernel<<<dim3(2048, 2), blk, 0, stream>>>(query, memory, Kp, Ap);
    transpose_cvt_kernel<<<dim3(16, 16, 4), blk, 0, stream>>>(
        Wq, Wk, Wv, Wo, WTq, WTk, WTv, WTo);

    dim3 gg(16, 32);
    // Q scaled by DH^-0.5 * log2(e): softmax runs in exp2 domain.
    gemm_kernel<bf16><<<gg, blk, 0, stream>>>(Kp, WTq, bq, Qp, 0.18033688f, 0);
    gemm_kv_kernel<<<gg, blk, 0, stream>>>(Ap, WTk, WTv, bk, bv, Kp, Vtp);
    attn_kernel<<<dim3(16, 16, 2), dim3(512), 0, stream>>>(Qp, Kp, Vtp, mbias, Ap);
    gemm_kernel<float><<<gg, blk, 0, stream>>>(Ap, WTo, bo, out, 1.0f, 0);
}